// Round 1
// baseline (665.589 us; speedup 1.0000x reference)
//
#include <hip/hip_runtime.h>
#include <stdint.h>

#define TPB 256

typedef __attribute__((ext_vector_type(8))) short bf16x8;
typedef __attribute__((ext_vector_type(4))) float f32x4;
typedef __attribute__((ext_vector_type(4))) unsigned short us4;

static __device__ __forceinline__ unsigned short f2bf(float f) {
  union { float f; uint32_t u; } v; v.f = f;
  return (unsigned short)((v.u + 0x7fffu + ((v.u >> 16) & 1u)) >> 16);
}

static __device__ __forceinline__ void gl_lds16(const void* g, void* l) {
  __builtin_amdgcn_global_load_lds(
      (const __attribute__((address_space(1))) void*)g,
      (__attribute__((address_space(3))) void*)l, 16, 0, 0);
}

// ---------------------------------------------------------------------------
// Shared 4-layer MLP: x (128 rows x 128 cols, bf16, swizzled in xb) through
// 3x (Linear+bias+silu) + final Linear (no bias). Weights come from ws as
// pre-transposed, pre-swizzled bf16 (32KB per layer), staged linearly into Wb.
// Wave w owns rows [w*32, w*32+32). MFMA operands swapped (A=W^T frag,
// B=x frag) so each lane's D holds 4 consecutive output columns.
// ---------------------------------------------------------------------------
static __device__ __forceinline__ void run_mlp(
    char* __restrict__ Wb, char* __restrict__ xb, const char* __restrict__ wt4,
    const float* __restrict__ b1, const float* __restrict__ b2,
    const float* __restrict__ b3, float* __restrict__ outRow, int tid)
{
  const int lane = tid & 63;
  const int wave = tid >> 6;
  const int l15 = lane & 15;
  const int q = lane >> 4;
  const int swz = (lane & 7) << 4;

  #pragma unroll
  for (int L = 0; L < 4; ++L) {
    __syncthreads();  // previous readers of Wb are done
    {
      const char* src = wt4 + L * 32768;
      for (int c = wave; c < 32; c += 4)
        gl_lds16(src + c * 1024 + lane * 16, Wb + c * 1024);
    }
    __syncthreads();  // staging complete (vmcnt drained) + x writes visible

    f32x4 acc[2][8];
    #pragma unroll
    for (int rt = 0; rt < 2; ++rt)
      #pragma unroll
      for (int ct = 0; ct < 8; ++ct) {
        f32x4 z = {0.f, 0.f, 0.f, 0.f};
        acc[rt][ct] = z;
      }

    #pragma unroll
    for (int ks = 0; ks < 4; ++ks) {
      const int kb = ks * 64 + q * 16;  // byte offset along K
      bf16x8 xf0 = *(const bf16x8*)(xb + (((wave * 32 + l15) * 256 + kb) ^ swz));
      bf16x8 xf1 = *(const bf16x8*)(xb + (((wave * 32 + 16 + l15) * 256 + kb) ^ swz));
      #pragma unroll
      for (int ct = 0; ct < 8; ++ct) {
        bf16x8 wf = *(const bf16x8*)(Wb + (((ct * 16 + l15) * 256 + kb) ^ swz));
        acc[0][ct] = __builtin_amdgcn_mfma_f32_16x16x32_bf16(wf, xf0, acc[0][ct], 0, 0, 0);
        acc[1][ct] = __builtin_amdgcn_mfma_f32_16x16x32_bf16(wf, xf1, acc[1][ct], 0, 0, 0);
      }
    }

    if (L == 0 || L == 1 || L == 2) {
      const float* bp = (L == 0) ? b1 : (L == 1) ? b2 : b3;
      #pragma unroll
      for (int ct = 0; ct < 8; ++ct) {
        f32x4 bv = *(const f32x4*)(bp + ct * 16 + q * 4);
        #pragma unroll
        for (int rt = 0; rt < 2; ++rt) {
          us4 p;
          #pragma unroll
          for (int r = 0; r < 4; ++r) {
            float v = acc[rt][ct][r] + bv[r];
            p[r] = f2bf(v * (1.0f / (1.0f + __expf(-v))));
          }
          const int row = wave * 32 + rt * 16 + l15;
          *(us4*)(xb + ((row * 256 + (ct * 16 + q * 4) * 2) ^ swz)) = p;
        }
      }
    } else {
      #pragma unroll
      for (int rt = 0; rt < 2; ++rt) {
        const int row = wave * 32 + rt * 16 + l15;
        #pragma unroll
        for (int ct = 0; ct < 8; ++ct) {
          *(f32x4*)(outRow + (size_t)row * 128 + ct * 16 + q * 4) = acc[rt][ct];
        }
      }
    }
  }
}

// ---------------------------------------------------------------------------
// Edge branch: x0 = (e_rbf @ We) * m_ji, then 4-layer MLP.
// ---------------------------------------------------------------------------
__global__ __launch_bounds__(TPB, 2) void edge_kernel(
    const float* __restrict__ m_ji, const float* __restrict__ e_rbf,
    const float* __restrict__ We,
    const float* __restrict__ b1, const float* __restrict__ b2,
    const float* __restrict__ b3,
    const char* __restrict__ wt4, float* __restrict__ out)
{
  __shared__ __align__(16) char Wb[32768];
  __shared__ __align__(16) char xb[32768];
  const int tid = threadIdx.x;
  const int rowbase = blockIdx.x * 128;

  // stage We (6x128 f32) into Wb front
  float* WeF = (float*)Wb;
  for (int i = tid; i < 768; i += TPB) WeF[i] = We[i];
  __syncthreads();

  // projection + gate, write bf16 x0 into xb (swizzled)
  #pragma unroll 4
  for (int it = 0; it < 16; ++it) {
    const int rowL = it * 8 + (tid >> 5);
    const int col0 = (tid & 31) * 4;
    const int grow = rowbase + rowL;
    f32x4 m = *(const f32x4*)(m_ji + (size_t)grow * 128 + col0);
    const float* ep = e_rbf + (size_t)grow * 6;
    const float e0 = ep[0], e1 = ep[1], e2 = ep[2], e3 = ep[3], e4 = ep[4], e5 = ep[5];
    us4 p;
    #pragma unroll
    for (int j = 0; j < 4; ++j) {
      const int c = col0 + j;
      float s = e0 * WeF[c] + e1 * WeF[128 + c] + e2 * WeF[256 + c]
              + e3 * WeF[384 + c] + e4 * WeF[512 + c] + e5 * WeF[640 + c];
      p[j] = f2bf(s * m[j]);
    }
    *(us4*)(xb + ((rowL * 256 + col0 * 2) ^ ((rowL & 7) << 4))) = p;
  }

  run_mlp(Wb, xb, wt4, b1, b2, b3, out + (size_t)rowbase * 128, tid);
}

// ---------------------------------------------------------------------------
// Angle branch: x0 = (a_sbf @ Wa) * (m_ji[kj] + m_ji[ji]), then 4-layer MLP.
// Projection done with MFMA (K padded 42->64).
// ---------------------------------------------------------------------------
__global__ __launch_bounds__(TPB, 2) void angle_kernel(
    const float* __restrict__ m_ji, const float* __restrict__ a_sbf,
    const int* __restrict__ kj, const int* __restrict__ ji,
    const float* __restrict__ b1, const float* __restrict__ b2,
    const float* __restrict__ b3,
    const char* __restrict__ wt4, const char* __restrict__ waT,
    float* __restrict__ out)
{
  __shared__ __align__(16) char Wb[32768];  // [0,16K): a_sbf tile, [16K,32K): Wa^T
  __shared__ __align__(16) char xb[32768];
  const int tid = threadIdx.x;
  const int rowbase = blockIdx.x * 128;
  const int lane = tid & 63, wave = tid >> 6;
  const int l15 = lane & 15, q = lane >> 4;
  const int swz = (lane & 7) << 4;

  // stage Wa^T (16KB, pre-swizzled) into Wb+16K
  for (int c = wave; c < 16; c += 4)
    gl_lds16(waT + c * 1024 + lane * 16, Wb + 16384 + c * 1024);

  // stage a_sbf rows -> bf16 [128][64] swizzled (pad 42->64 with zeros)
  {
    const int row = tid >> 1;
    const int c0 = (tid & 1) * 32;
    const float* src = a_sbf + (size_t)(rowbase + row) * 42;
    const int rs = (row & 7) << 4;
    #pragma unroll
    for (int cc = 0; cc < 32; cc += 4) {
      const int col = c0 + cc;
      us4 p;
      #pragma unroll
      for (int jj = 0; jj < 4; ++jj) {
        const int k = col + jj;
        p[jj] = (k < 42) ? f2bf(src[k]) : (unsigned short)0;
      }
      *(us4*)(Wb + ((row * 128 + col * 2) ^ rs)) = p;
    }
  }
  __syncthreads();

  // projection MFMA: acc = a_sbf @ Wa
  f32x4 acc[2][8];
  #pragma unroll
  for (int rt = 0; rt < 2; ++rt)
    #pragma unroll
    for (int ct = 0; ct < 8; ++ct) {
      f32x4 z = {0.f, 0.f, 0.f, 0.f};
      acc[rt][ct] = z;
    }

  #pragma unroll
  for (int ks = 0; ks < 2; ++ks) {
    const int kb = ks * 64 + q * 16;
    bf16x8 xf0 = *(const bf16x8*)(Wb + (((wave * 32 + l15) * 128 + kb) ^ swz));
    bf16x8 xf1 = *(const bf16x8*)(Wb + (((wave * 32 + 16 + l15) * 128 + kb) ^ swz));
    #pragma unroll
    for (int ct = 0; ct < 8; ++ct) {
      bf16x8 wf = *(const bf16x8*)(Wb + 16384 + (((ct * 16 + l15) * 128 + kb) ^ swz));
      acc[0][ct] = __builtin_amdgcn_mfma_f32_16x16x32_bf16(wf, xf0, acc[0][ct], 0, 0, 0);
      acc[1][ct] = __builtin_amdgcn_mfma_f32_16x16x32_bf16(wf, xf1, acc[1][ct], 0, 0, 0);
    }
  }

  // gate by gathered messages and write bf16 x0 into xb
  #pragma unroll
  for (int rt = 0; rt < 2; ++rt) {
    const int row = wave * 32 + rt * 16 + l15;
    const int gr = rowbase + row;
    const float* pk = m_ji + (size_t)kj[gr] * 128;
    const float* pj = m_ji + (size_t)ji[gr] * 128;
    #pragma unroll
    for (int ct = 0; ct < 8; ++ct) {
      const int c0 = ct * 16 + q * 4;
      f32x4 ga = *(const f32x4*)(pk + c0);
      f32x4 gb = *(const f32x4*)(pj + c0);
      us4 p;
      #pragma unroll
      for (int r = 0; r < 4; ++r)
        p[r] = f2bf(acc[rt][ct][r] * (ga[r] + gb[r]));
      *(us4*)(xb + ((row * 256 + c0 * 2) ^ swz)) = p;
    }
  }

  run_mlp(Wb, xb, wt4, b1, b2, b3, out + (size_t)rowbase * 128, tid);
}

// ---------------------------------------------------------------------------
// Prep: bf16-convert + transpose + XOR-swizzle all weights into d_ws.
// ws layout: [0,256K): We1..We4,Wa1..Wa4 (32KB each, W^T[n][k] bf16, swizzled)
//            [256K, 272K): Wa^T [128][64] bf16 (K padded to 64), swizzled
// ---------------------------------------------------------------------------
__global__ void prep_kernel(
    const float* __restrict__ W0, const float* __restrict__ W1,
    const float* __restrict__ W2, const float* __restrict__ W3,
    const float* __restrict__ W4, const float* __restrict__ W5,
    const float* __restrict__ W6, const float* __restrict__ W7,
    const float* __restrict__ Wa, char* __restrict__ ws)
{
  const int gid = blockIdx.x * TPB + threadIdx.x;
  if (gid < 8 * 16384) {
    const int m = gid >> 14;
    const int e = gid & 16383;
    const int n = e >> 7, k = e & 127;
    const float* W;
    switch (m) {
      case 0: W = W0; break; case 1: W = W1; break;
      case 2: W = W2; break; case 3: W = W3; break;
      case 4: W = W4; break; case 5: W = W5; break;
      case 6: W = W6; break; default: W = W7; break;
    }
    *(unsigned short*)(ws + m * 32768 + ((n * 256 + k * 2) ^ ((n & 7) << 4))) =
        f2bf(W[k * 128 + n]);
  } else {
    const int g = gid - 8 * 16384;
    if (g < 128 * 64) {
      const int n = g >> 6, k = g & 63;
      *(unsigned short*)(ws + 262144 + ((n * 128 + k * 2) ^ ((n & 7) << 4))) =
          (k < 42) ? f2bf(Wa[k * 128 + n]) : (unsigned short)0;
    }
  }
}

extern "C" void kernel_launch(void* const* d_in, const int* in_sizes, int n_in,
                              void* d_out, int out_size, void* d_ws, size_t ws_size,
                              hipStream_t stream) {
  (void)in_sizes; (void)n_in; (void)out_size; (void)ws_size;
  const float* m_ji  = (const float*)d_in[0];
  const float* e_rbf = (const float*)d_in[1];
  const float* a_sbf = (const float*)d_in[2];
  const int*   kj    = (const int*)d_in[4];
  const int*   ji    = (const int*)d_in[5];
  const float* We    = (const float*)d_in[6];
  const float* We1   = (const float*)d_in[7];
  const float* be1   = (const float*)d_in[8];
  const float* We2   = (const float*)d_in[9];
  const float* be2   = (const float*)d_in[10];
  const float* We3   = (const float*)d_in[11];
  const float* be3   = (const float*)d_in[12];
  const float* We4   = (const float*)d_in[13];
  const float* Wa    = (const float*)d_in[14];
  const float* Wa1   = (const float*)d_in[15];
  const float* ba1   = (const float*)d_in[16];
  const float* Wa2   = (const float*)d_in[17];
  const float* ba2   = (const float*)d_in[18];
  const float* Wa3   = (const float*)d_in[19];
  const float* ba3   = (const float*)d_in[20];
  const float* Wa4   = (const float*)d_in[21];
  char* ws = (char*)d_ws;
  float* out = (float*)d_out;

  prep_kernel<<<(8 * 16384 + 128 * 64 + TPB - 1) / TPB, TPB, 0, stream>>>(
      We1, We2, We3, We4, Wa1, Wa2, Wa3, Wa4, Wa, ws);
  edge_kernel<<<262144 / 128, TPB, 0, stream>>>(
      m_ji, e_rbf, We, be1, be2, be3, ws, out);
  angle_kernel<<<1048576 / 128, TPB, 0, stream>>>(
      m_ji, a_sbf, kj, ji, ba1, ba2, ba3, ws + 131072, ws + 262144,
      out + (size_t)262144 * 128);
}

// Round 2
// 618.852 us; speedup vs baseline: 1.0755x; 1.0755x over previous
//
#include <hip/hip_runtime.h>
#include <stdint.h>

#define TPB 512

typedef __attribute__((ext_vector_type(8))) short bf16x8;
typedef __attribute__((ext_vector_type(4))) float f32x4;

static __device__ __forceinline__ unsigned short f2bf_u(float f) {
  __bf16 h = (__bf16)f;
  return __builtin_bit_cast(unsigned short, h);
}
static __device__ __forceinline__ uint32_t pack2bf(float a, float b) {
  return (uint32_t)f2bf_u(a) | ((uint32_t)f2bf_u(b) << 16);
}
static __device__ __forceinline__ float silu_f(float v) {
  // v * sigmoid(v) = v / (1 + exp2(-v*log2e)); hw exp2 + hw rcp (~1 ulp each)
  float e = __builtin_amdgcn_exp2f(v * -1.44269504088896341f);
  return v * __builtin_amdgcn_rcpf(1.0f + e);
}

static __device__ __forceinline__ void gl_lds16(const void* g, void* l) {
  __builtin_amdgcn_global_load_lds(
      (const __attribute__((address_space(1))) void*)g,
      (__attribute__((address_space(3))) void*)l, 16, 0, 0);
}

// ---------------------------------------------------------------------------
// Shared 4-layer MLP: x (128 rows x 128 cols bf16, XOR-swizzled in xb) through
// 3x (Linear+bias+silu) + final Linear (no bias, f32 nt-store to global).
// 8 waves; wave w owns rows [w*16, w*16+16) — xb is wave-private, only Wb
// staging needs barriers. Weights pre-transposed+swizzled bf16 in ws.
// MFMA operands swapped (A=W^T frag, B=x frag): lane's D = 4 consecutive
// output cols of one x-row.
// ---------------------------------------------------------------------------
static __device__ __forceinline__ void run_mlp(
    char* __restrict__ Wb, char* __restrict__ xb, const char* __restrict__ wt4,
    const float* __restrict__ b1, const float* __restrict__ b2,
    const float* __restrict__ b3, float* __restrict__ outRow, int tid)
{
  const int lane = tid & 63;
  const int wave = tid >> 6;      // 0..7
  const int l15 = lane & 15;
  const int q = lane >> 4;
  const int swz = (lane & 7) << 4;
  const int row = wave * 16 + l15;

  #pragma unroll
  for (int L = 0; L < 4; ++L) {
    __syncthreads();  // previous readers of Wb are done
    {
      const char* src = wt4 + L * 32768;
      #pragma unroll
      for (int c = wave; c < 32; c += 8)
        gl_lds16(src + c * 1024 + lane * 16, Wb + c * 1024);
    }
    __syncthreads();  // staging complete (vmcnt drained at barrier)

    f32x4 acc[8];
    #pragma unroll
    for (int ct = 0; ct < 8; ++ct) { f32x4 z = {0.f,0.f,0.f,0.f}; acc[ct] = z; }

    #pragma unroll
    for (int ks = 0; ks < 4; ++ks) {
      const int kb = ks * 64 + q * 16;
      bf16x8 xf = *(const bf16x8*)(xb + ((row * 256 + kb) ^ swz));
      #pragma unroll
      for (int ct = 0; ct < 8; ++ct) {
        bf16x8 wf = *(const bf16x8*)(Wb + (((ct * 16 + l15) * 256 + kb) ^ swz));
        acc[ct] = __builtin_amdgcn_mfma_f32_16x16x32_bf16(wf, xf, acc[ct], 0, 0, 0);
      }
    }

    if (L < 3) {
      const float* bp = (L == 0) ? b1 : (L == 1) ? b2 : b3;
      #pragma unroll
      for (int ct = 0; ct < 8; ++ct) {
        f32x4 bv = *(const f32x4*)(bp + ct * 16 + q * 4);
        float v0 = silu_f(acc[ct][0] + bv[0]);
        float v1 = silu_f(acc[ct][1] + bv[1]);
        float v2 = silu_f(acc[ct][2] + bv[2]);
        float v3 = silu_f(acc[ct][3] + bv[3]);
        uint2 u; u.x = pack2bf(v0, v1); u.y = pack2bf(v2, v3);
        *(uint2*)(xb + ((row * 256 + (ct * 16 + q * 4) * 2) ^ swz)) = u;
      }
    } else {
      #pragma unroll
      for (int ct = 0; ct < 8; ++ct)
        __builtin_nontemporal_store(acc[ct],
            (f32x4*)(outRow + (size_t)row * 128 + ct * 16 + q * 4));
    }
  }
}

// ---------------------------------------------------------------------------
// Edge branch: x0 = (e_rbf @ We) * m_ji, then 4-layer MLP.
// ---------------------------------------------------------------------------
__global__ __launch_bounds__(TPB, 4) void edge_kernel(
    const float* __restrict__ m_ji, const float* __restrict__ e_rbf,
    const float* __restrict__ We,
    const float* __restrict__ b1, const float* __restrict__ b2,
    const float* __restrict__ b3,
    const char* __restrict__ wt4, float* __restrict__ out)
{
  __shared__ __align__(16) char Wb[32768];
  __shared__ __align__(16) char xb[32768];
  const int tid = threadIdx.x;
  const int rowbase = blockIdx.x * 128;

  // stage We (6x128 f32) into Wb front
  float* WeF = (float*)Wb;
  for (int i = tid; i < 768; i += TPB) WeF[i] = We[i];
  __syncthreads();

  // projection + gate, write bf16 x0 into xb (swizzled)
  #pragma unroll
  for (int it = 0; it < 8; ++it) {
    const int rowL = it * 16 + (tid >> 5);
    const int col0 = (tid & 31) * 4;
    const int grow = rowbase + rowL;
    f32x4 m = *(const f32x4*)(m_ji + (size_t)grow * 128 + col0);
    const float* ep = e_rbf + (size_t)grow * 6;
    const float e0 = ep[0], e1 = ep[1], e2 = ep[2], e3 = ep[3], e4 = ep[4], e5 = ep[5];
    float s[4];
    #pragma unroll
    for (int j = 0; j < 4; ++j) {
      const int c = col0 + j;
      s[j] = (e0 * WeF[c] + e1 * WeF[128 + c] + e2 * WeF[256 + c]
            + e3 * WeF[384 + c] + e4 * WeF[512 + c] + e5 * WeF[640 + c]) * m[j];
    }
    uint2 u; u.x = pack2bf(s[0], s[1]); u.y = pack2bf(s[2], s[3]);
    *(uint2*)(xb + ((rowL * 256 + col0 * 2) ^ ((rowL & 7) << 4))) = u;
  }

  run_mlp(Wb, xb, wt4, b1, b2, b3, out + (size_t)rowbase * 128, tid);
}

// ---------------------------------------------------------------------------
// Angle branch: x0 = (a_sbf @ Wa) * (m_ji[kj] + m_ji[ji]), then 4-layer MLP.
// Projection via MFMA (K padded 42->64).
// ---------------------------------------------------------------------------
__global__ __launch_bounds__(TPB, 4) void angle_kernel(
    const float* __restrict__ m_ji, const float* __restrict__ a_sbf,
    const int* __restrict__ kj, const int* __restrict__ ji,
    const float* __restrict__ b1, const float* __restrict__ b2,
    const float* __restrict__ b3,
    const char* __restrict__ wt4, const char* __restrict__ waT,
    float* __restrict__ out)
{
  __shared__ __align__(16) char Wb[32768];  // [0,16K): a_sbf tile, [16K,32K): Wa^T
  __shared__ __align__(16) char xb[32768];
  const int tid = threadIdx.x;
  const int rowbase = blockIdx.x * 128;
  const int lane = tid & 63, wave = tid >> 6;
  const int l15 = lane & 15, q = lane >> 4;
  const int swz = (lane & 7) << 4;
  const int row = wave * 16 + l15;
  const int gr = rowbase + row;

  // load gather indices early (latency hides under staging)
  const int ikj = kj[gr], iji = ji[gr];

  // stage Wa^T (16KB, pre-swizzled) into Wb+16K
  #pragma unroll
  for (int c = wave; c < 16; c += 8)
    gl_lds16(waT + c * 1024 + lane * 16, Wb + 16384 + c * 1024);

  // zero-fill a_sbf tile region (covers the 42..63 K-pad), then scatter-fill
  for (int i = tid; i < 2048; i += TPB) {
    uint2 z; z.x = 0u; z.y = 0u;
    *(uint2*)(Wb + i * 8) = z;
  }
  __syncthreads();
  {
    const float* base = a_sbf + (size_t)rowbase * 42;
    for (int idx = tid; idx < 128 * 42; idx += TPB) {
      const int r = idx / 42;
      const int c = idx - r * 42;
      float v = __builtin_nontemporal_load(base + idx);
      *(unsigned short*)(Wb + ((r * 128 + c * 2) ^ ((r & 7) << 4))) = f2bf_u(v);
    }
  }
  __syncthreads();

  // projection MFMA: acc = a_sbf @ Wa   (rows [128][K=64] bf16)
  f32x4 acc[8];
  #pragma unroll
  for (int ct = 0; ct < 8; ++ct) { f32x4 z = {0.f,0.f,0.f,0.f}; acc[ct] = z; }

  #pragma unroll
  for (int ks = 0; ks < 2; ++ks) {
    const int kb = ks * 64 + q * 16;
    bf16x8 xf = *(const bf16x8*)(Wb + ((row * 128 + kb) ^ swz));
    #pragma unroll
    for (int ct = 0; ct < 8; ++ct) {
      bf16x8 wf = *(const bf16x8*)(Wb + 16384 + (((ct * 16 + l15) * 128 + kb) ^ swz));
      acc[ct] = __builtin_amdgcn_mfma_f32_16x16x32_bf16(wf, xf, acc[ct], 0, 0, 0);
    }
  }

  // gate by gathered messages and write bf16 x0 into xb
  {
    const float* pk = m_ji + (size_t)ikj * 128;
    const float* pj = m_ji + (size_t)iji * 128;
    #pragma unroll
    for (int ct = 0; ct < 8; ++ct) {
      const int c0 = ct * 16 + q * 4;
      f32x4 ga = *(const f32x4*)(pk + c0);
      f32x4 gb = *(const f32x4*)(pj + c0);
      uint2 u;
      u.x = pack2bf(acc[ct][0] * (ga[0] + gb[0]), acc[ct][1] * (ga[1] + gb[1]));
      u.y = pack2bf(acc[ct][2] * (ga[2] + gb[2]), acc[ct][3] * (ga[3] + gb[3]));
      *(uint2*)(xb + ((row * 256 + c0 * 2) ^ swz)) = u;
    }
  }

  run_mlp(Wb, xb, wt4, b1, b2, b3, out + (size_t)rowbase * 128, tid);
}

// ---------------------------------------------------------------------------
// Prep: bf16-convert + transpose + XOR-swizzle all weights into d_ws.
// ws layout: [0,256K): We1..We4,Wa1..Wa4 (32KB each, W^T[n][k] bf16, swizzled)
//            [256K, 272K): Wa^T [128][64] bf16 (K padded to 64), swizzled
// ---------------------------------------------------------------------------
__global__ void prep_kernel(
    const float* __restrict__ W0, const float* __restrict__ W1,
    const float* __restrict__ W2, const float* __restrict__ W3,
    const float* __restrict__ W4, const float* __restrict__ W5,
    const float* __restrict__ W6, const float* __restrict__ W7,
    const float* __restrict__ Wa, char* __restrict__ ws)
{
  const int gid = blockIdx.x * 256 + threadIdx.x;
  if (gid < 8 * 16384) {
    const int m = gid >> 14;
    const int e = gid & 16383;
    const int n = e >> 7, k = e & 127;
    const float* W;
    switch (m) {
      case 0: W = W0; break; case 1: W = W1; break;
      case 2: W = W2; break; case 3: W = W3; break;
      case 4: W = W4; break; case 5: W = W5; break;
      case 6: W = W6; break; default: W = W7; break;
    }
    *(unsigned short*)(ws + m * 32768 + ((n * 256 + k * 2) ^ ((n & 7) << 4))) =
        f2bf_u(W[k * 128 + n]);
  } else {
    const int g = gid - 8 * 16384;
    if (g < 128 * 64) {
      const int n = g >> 6, k = g & 63;
      *(unsigned short*)(ws + 262144 + ((n * 128 + k * 2) ^ ((n & 7) << 4))) =
          (k < 42) ? f2bf_u(Wa[k * 128 + n]) : (unsigned short)0;
    }
  }
}

extern "C" void kernel_launch(void* const* d_in, const int* in_sizes, int n_in,
                              void* d_out, int out_size, void* d_ws, size_t ws_size,
                              hipStream_t stream) {
  (void)in_sizes; (void)n_in; (void)out_size; (void)ws_size;
  const float* m_ji  = (const float*)d_in[0];
  const float* e_rbf = (const float*)d_in[1];
  const float* a_sbf = (const float*)d_in[2];
  const int*   kj    = (const int*)d_in[4];
  const int*   ji    = (const int*)d_in[5];
  const float* We    = (const float*)d_in[6];
  const float* We1   = (const float*)d_in[7];
  const float* be1   = (const float*)d_in[8];
  const float* We2   = (const float*)d_in[9];
  const float* be2   = (const float*)d_in[10];
  const float* We3   = (const float*)d_in[11];
  const float* be3   = (const float*)d_in[12];
  const float* We4   = (const float*)d_in[13];
  const float* Wa    = (const float*)d_in[14];
  const float* Wa1   = (const float*)d_in[15];
  const float* ba1   = (const float*)d_in[16];
  const float* Wa2   = (const float*)d_in[17];
  const float* ba2   = (const float*)d_in[18];
  const float* Wa3   = (const float*)d_in[19];
  const float* ba3   = (const float*)d_in[20];
  const float* Wa4   = (const float*)d_in[21];
  char* ws = (char*)d_ws;
  float* out = (float*)d_out;

  prep_kernel<<<(8 * 16384 + 128 * 64 + 255) / 256, 256, 0, stream>>>(
      We1, We2, We3, We4, Wa1, Wa2, Wa3, Wa4, Wa, ws);
  edge_kernel<<<262144 / 128, TPB, 0, stream>>>(
      m_ji, e_rbf, We, be1, be2, be3, ws, out);
  angle_kernel<<<1048576 / 128, TPB, 0, stream>>>(
      m_ji, a_sbf, kj, ji, ba1, ba2, ba3, ws + 131072, ws + 262144,
      out + (size_t)262144 * 128);
}